// Round 1
// baseline (395.338 us; speedup 1.0000x reference)
//
#include <hip/hip_runtime.h>
#include <math.h>

// Problem constants (from reference setup_inputs)
#define B_    128
#define C_    768
#define O_    192
#define H_    17
#define HW_   289                 // 17*17
#define N_IN  (128*768*289)       // 28,409,856
#define N_OUT (128*192*289)       // 7,102,464
#define PLANES (128*768)          // 98,304
#define QN_   127.0f

// ---------------------------------------------------------------------------
// ws layout (bytes):
//   0      : u32 cnt[0] = absmax(|x|) bits
//   4      : i32 cnt[1] = max |pooled_sum| (integer)
//   8      : u32 cnt[2] = absmax(relu(out)) bits
//   1024   : f32 b_int[192]
//   2048   : f32 scale_o[192]   (= w_sf * s1)
//   4096   : f32 w_qT[768*192]  (w_int, transposed [c][o])
//   1MiB   : i16 pooled[128*768*289]   (56.8 MB)
// total ~57.9 MB
// ---------------------------------------------------------------------------

__global__ void k_init(unsigned* cnt) {
    if (threadIdx.x < 3) cnt[threadIdx.x] = 0u;
}

__global__ void k_absmax_x(const float4* __restrict__ x4, int n4, unsigned* cnt) {
    float m = 0.f;
    for (int i = blockIdx.x * blockDim.x + threadIdx.x; i < n4;
         i += gridDim.x * blockDim.x) {
        float4 v = x4[i];
        m = fmaxf(m, fmaxf(fmaxf(fabsf(v.x), fabsf(v.y)),
                           fmaxf(fabsf(v.z), fabsf(v.w))));
    }
#pragma unroll
    for (int off = 32; off; off >>= 1) m = fmaxf(m, __shfl_down(m, off));
    __shared__ float sm[4];
    int lane = threadIdx.x & 63, wv = threadIdx.x >> 6;
    if (lane == 0) sm[wv] = m;
    __syncthreads();
    if (threadIdx.x == 0) {
        float bm = fmaxf(fmaxf(sm[0], sm[1]), fmaxf(sm[2], sm[3]));
        atomicMax(cnt + 0, __float_as_uint(bm));  // bits order == float order for >=0
    }
}

// Quantize x -> int8 codes, 3x3 zero-padded pooling (integer sums), store int16
// pooled sums, track global max |pooled_sum|.
__global__ void k_quant_pool(const float* __restrict__ x,
                             short* __restrict__ pooled, unsigned* cnt) {
    __shared__ float q[HW_];
    __shared__ int smax[4];
    const float s0 = fmaxf(__uint_as_float(cnt[0]) / QN_, 1e-8f);
    int tmax = 0;
    const int p0 = blockIdx.x * 48;  // 2048 blocks * 48 = 98,304 planes
    for (int p = p0; p < p0 + 48; ++p) {
        const float* xp = x + (size_t)p * HW_;
        for (int t = threadIdx.x; t < HW_; t += 256) {
            float v = rintf(xp[t] / s0);
            q[t] = fminf(fmaxf(v, -128.f), 127.f);
        }
        __syncthreads();
        short* pp = pooled + (size_t)p * HW_;
        for (int t = threadIdx.x; t < HW_; t += 256) {
            int h = t / 17, w = t - h * 17;
            int h0 = (h > 0) ? h - 1 : h, h1 = (h < 16) ? h + 1 : h;
            int w0 = (w > 0) ? w - 1 : w, w1 = (w < 16) ? w + 1 : w;
            float s = 0.f;
            for (int hh = h0; hh <= h1; ++hh)
                for (int ww = w0; ww <= w1; ++ww) s += q[hh * 17 + ww];
            int si = (int)s;  // exact: |si| <= 1152
            pp[t] = (short)si;
            int a = si < 0 ? -si : si;
            tmax = a > tmax ? a : tmax;
        }
        __syncthreads();
    }
#pragma unroll
    for (int off = 32; off; off >>= 1) {
        int o = __shfl_down(tmax, off);
        tmax = o > tmax ? o : tmax;
    }
    int lane = threadIdx.x & 63, wv = threadIdx.x >> 6;
    if (lane == 0) smax[wv] = tmax;
    __syncthreads();
    if (threadIdx.x == 0) {
        int bm = smax[0];
        bm = smax[1] > bm ? smax[1] : bm;
        bm = smax[2] > bm ? smax[2] : bm;
        bm = smax[3] > bm ? smax[3] : bm;
        atomicMax((int*)(cnt + 1), bm);
    }
}

// Fold BN into conv, per-channel weight quant, b_int, output scales.
__global__ void k_weights(const float* __restrict__ conv_w,
                          const float* __restrict__ g,
                          const float* __restrict__ beta,
                          const float* __restrict__ mu,
                          const float* __restrict__ var,
                          const unsigned* __restrict__ cnt,
                          float* __restrict__ w_qT, float* __restrict__ b_int,
                          float* __restrict__ scale_o) {
    const int o = blockIdx.x;
    const float stdv = sqrtf(var[o] + 1e-5f);
    const float r = g[o] / stdv;
    const float* wo = conv_w + o * C_;
    float m = 0.f;
    for (int c = threadIdx.x; c < C_; c += 256) m = fmaxf(m, fabsf(wo[c] * r));
#pragma unroll
    for (int off = 32; off; off >>= 1) m = fmaxf(m, __shfl_down(m, off));
    __shared__ float sm[4];
    __shared__ float swsf;
    int lane = threadIdx.x & 63, wv = threadIdx.x >> 6;
    if (lane == 0) sm[wv] = m;
    __syncthreads();
    if (threadIdx.x == 0) {
        float bm = fmaxf(fmaxf(sm[0], sm[1]), fmaxf(sm[2], sm[3]));
        swsf = fmaxf(bm / QN_, 1e-8f);
    }
    __syncthreads();
    const float wsf = swsf;
    for (int c = threadIdx.x; c < C_; c += 256) {
        float wi = rintf(wo[c] * r / wsf);
        w_qT[c * O_ + o] = fminf(fmaxf(wi, -128.f), 127.f);
    }
    if (threadIdx.x == 0) {
        float s0 = fmaxf(__uint_as_float(cnt[0]) / QN_, 1e-8f);
        float maxx2 = ((float)((const int*)cnt)[1] / 9.0f) * s0;  // monotone => exact
        float s1 = fmaxf(maxx2 / QN_, 1e-8f);
        float bf = beta[o] - g[o] * mu[o] / stdv;
        b_int[o] = rintf(bf / (wsf * s1));
        scale_o[o] = wsf * s1;
    }
}

// fp32 GEMM: out[b,o,hw] = relu((sum_c xi[b,c,hw]*w_int[o,c] + b_int[o]) * scale_o[o])
// xi computed on the fly from pooled int16. All values are exact small integers
// (|sum| < 2^24) so fp32 accumulation is bit-exact.
#define BM 64
#define BN 64
#define BK 16
__launch_bounds__(256) __global__
void k_gemm(const short* __restrict__ pooled, const float* __restrict__ w_qT,
            const float* __restrict__ b_int, const float* __restrict__ scale_o,
            unsigned* cnt, float* __restrict__ out) {
    __shared__ float As[BK][BM];
    __shared__ float Bs[BK][BN];
    const int b = blockIdx.z;
    const int hw0 = blockIdx.x * BM;   // 5 tiles cover 289 (padded to 320)
    const int o0 = blockIdx.y * BN;    // 3 tiles cover 192
    const float s0 = fmaxf(__uint_as_float(cnt[0]) / QN_, 1e-8f);
    const float s1 =
        fmaxf(((float)((const int*)cnt)[1] / 9.0f) * s0 / QN_, 1e-8f);
    const short* Ab = pooled + (size_t)b * C_ * HW_;
    const int tx = threadIdx.x & 15;  // m sub-tile
    const int ty = threadIdx.x >> 4;  // o sub-tile (and staging k index)
    float acc[4][4] = {};
    for (int k0 = 0; k0 < C_; k0 += BK) {
        const int c = k0 + ty;  // ty in [0,16) == BK
        const short* arow = Ab + (size_t)c * HW_;
#pragma unroll
        for (int j = 0; j < 4; ++j) {
            int hw = hw0 + tx * 4 + j;
            float xi = 0.f;
            if (hw < HW_) {
                float x2 = ((float)arow[hw] / 9.0f) * s0;
                xi = fminf(fmaxf(rintf(x2 / s1), -128.f), 127.f);
            }
            As[ty][tx * 4 + j] = xi;
        }
        const float* wrow = w_qT + (size_t)c * O_ + o0;
#pragma unroll
        for (int j = 0; j < 4; ++j) Bs[ty][tx * 4 + j] = wrow[tx * 4 + j];
        __syncthreads();
#pragma unroll
        for (int kk = 0; kk < BK; ++kk) {
            float4 av = *(const float4*)&As[kk][tx * 4];
            float4 bv = *(const float4*)&Bs[kk][ty * 4];
            float a[4] = {av.x, av.y, av.z, av.w};
            float w[4] = {bv.x, bv.y, bv.z, bv.w};
#pragma unroll
            for (int i = 0; i < 4; ++i)
#pragma unroll
                for (int j = 0; j < 4; ++j) acc[i][j] += a[i] * w[j];
        }
        __syncthreads();
    }
    float lmax = 0.f;
#pragma unroll
    for (int j = 0; j < 4; ++j) {
        int o = o0 + ty * 4 + j;
        float bi = b_int[o], sc = scale_o[o];
#pragma unroll
        for (int i = 0; i < 4; ++i) {
            int hw = hw0 + tx * 4 + i;
            if (hw < HW_) {
                float v = fmaxf((acc[i][j] + bi) * sc, 0.f);
                out[((size_t)b * O_ + o) * HW_ + hw] = v;
                lmax = fmaxf(lmax, v);
            }
        }
    }
#pragma unroll
    for (int off = 32; off; off >>= 1) lmax = fmaxf(lmax, __shfl_down(lmax, off));
    __shared__ float sm[4];
    int lane = threadIdx.x & 63, wv = threadIdx.x >> 6;
    if (lane == 0) sm[wv] = lmax;
    __syncthreads();
    if (threadIdx.x == 0) {
        float bm = fmaxf(fmaxf(sm[0], sm[1]), fmaxf(sm[2], sm[3]));
        atomicMax(cnt + 2, __float_as_uint(bm));
    }
}

// Final output quant: outq = clip(rint(out/s2),-128,127)*s2, plus s2 scalar.
__global__ void k_quant_out(float* __restrict__ out, const unsigned* __restrict__ cnt) {
    const float s2 = fmaxf(__uint_as_float(cnt[2]) / QN_, 1e-8f);
    float4* o4 = (float4*)out;
    const int n4 = N_OUT / 4;
    for (int i = blockIdx.x * blockDim.x + threadIdx.x; i < n4;
         i += gridDim.x * blockDim.x) {
        float4 v = o4[i];
        v.x = fminf(fmaxf(rintf(v.x / s2), -128.f), 127.f) * s2;
        v.y = fminf(fmaxf(rintf(v.y / s2), -128.f), 127.f) * s2;
        v.z = fminf(fmaxf(rintf(v.z / s2), -128.f), 127.f) * s2;
        v.w = fminf(fmaxf(rintf(v.w / s2), -128.f), 127.f) * s2;
        o4[i] = v;
    }
    if (blockIdx.x == 0 && threadIdx.x == 0) out[N_OUT] = s2;
}

extern "C" void kernel_launch(void* const* d_in, const int* in_sizes, int n_in,
                              void* d_out, int out_size, void* d_ws, size_t ws_size,
                              hipStream_t stream) {
    const float* x      = (const float*)d_in[0];
    const float* conv_w = (const float*)d_in[1];
    const float* g      = (const float*)d_in[2];
    const float* beta   = (const float*)d_in[3];
    const float* mu     = (const float*)d_in[4];
    const float* var    = (const float*)d_in[5];
    float* out = (float*)d_out;

    char* wsb = (char*)d_ws;
    unsigned* cnt   = (unsigned*)wsb;
    float* b_int    = (float*)(wsb + 1024);
    float* scale_o  = (float*)(wsb + 2048);
    float* w_qT     = (float*)(wsb + 4096);            // 589,824 B
    short* pooled   = (short*)(wsb + (1u << 20));      // 56,819,712 B

    k_init<<<1, 64, 0, stream>>>(cnt);
    k_absmax_x<<<2048, 256, 0, stream>>>((const float4*)x, N_IN / 4, cnt);
    k_quant_pool<<<2048, 256, 0, stream>>>(x, pooled, cnt);
    k_weights<<<O_, 256, 0, stream>>>(conv_w, g, beta, mu, var, cnt, w_qT, b_int,
                                      scale_o);
    dim3 ggrid(5, 3, B_);
    k_gemm<<<ggrid, 256, 0, stream>>>(pooled, w_qT, b_int, scale_o, cnt, out);
    k_quant_out<<<2048, 256, 0, stream>>>(out, cnt);
}

// Round 3
// 166.257 us; speedup vs baseline: 2.3779x; 2.3779x over previous
//
#include <hip/hip_runtime.h>
#include <math.h>

#define B_    128
#define C_    768
#define O_    192
#define HW_   289
#define N_IN  (128*768*289)
#define N_OUT (128*192*289)
#define QN_   127.0f

typedef __attribute__((ext_vector_type(8))) short bf16x8;
typedef __attribute__((ext_vector_type(4))) float f32x4;

// XOR swizzle within a 64B row: flip 16B-chunk-select bits (4..5) by row bits (6..7).
// Involution, row-preserving, 16B-alignment-preserving.
#define SWZ(b) ((b) ^ ((((b) >> 6) & 3) << 4))

// ws layout:
//  0     : cnt[0]=absmax(x) bits, cnt[1]=max|pooled| int, cnt[2]=absmax(out) bits
//  1024  : f32 b_int[192]
//  2048  : f32 scale_o[192]
//  3072  : u16 lut[2305]
//  8192  : u16 w_q bf16 image, [kt][o][cc] linear, 24*6144 u16 = 294912 B
//  1MiB  : i16 pooled[128*768*289]

__global__ void k_init(unsigned* cnt) {
    if (threadIdx.x < 3) cnt[threadIdx.x] = 0u;
}

__global__ void k_absmax_x(const float4* __restrict__ x4, int n4, unsigned* cnt) {
    float m = 0.f;
    for (int i = blockIdx.x * blockDim.x + threadIdx.x; i < n4;
         i += gridDim.x * blockDim.x) {
        float4 v = x4[i];
        m = fmaxf(m, fmaxf(fmaxf(fabsf(v.x), fabsf(v.y)),
                           fmaxf(fabsf(v.z), fabsf(v.w))));
    }
#pragma unroll
    for (int off = 32; off; off >>= 1) m = fmaxf(m, __shfl_down(m, off));
    __shared__ float sm[4];
    int lane = threadIdx.x & 63, wv = threadIdx.x >> 6;
    if (lane == 0) sm[wv] = m;
    __syncthreads();
    if (threadIdx.x == 0) {
        float bm = fmaxf(fmaxf(sm[0], sm[1]), fmaxf(sm[2], sm[3]));
        atomicMax(cnt + 0, __float_as_uint(bm));
    }
}

// Quantize to int8 codes + 3x3 zero-pad pooled integer sums (int16) + global max.
__global__ void k_quant_pool(const float* __restrict__ x,
                             short* __restrict__ pooled, unsigned* cnt) {
    __shared__ float q[1168];
    __shared__ int smax[4];
    const float s0 = fmaxf(__uint_as_float(cnt[0]) / QN_, 1e-8f);
    int tmax = 0;
    const int g0 = blockIdx.x * 12;   // 2048 blocks * 12 = 24576 groups of 4 planes
    for (int g = g0; g < g0 + 12; ++g) {
        __syncthreads();
        const float4* xg = (const float4*)(x + (size_t)g * 1156);
        for (int t = threadIdx.x; t < 289; t += 256) {
            float4 v = xg[t];
            float4 o;
            o.x = fminf(fmaxf(rintf(v.x / s0), -128.f), 127.f);
            o.y = fminf(fmaxf(rintf(v.y / s0), -128.f), 127.f);
            o.z = fminf(fmaxf(rintf(v.z / s0), -128.f), 127.f);
            o.w = fminf(fmaxf(rintf(v.w / s0), -128.f), 127.f);
            *(float4*)&q[t * 4] = o;
        }
        __syncthreads();
        short* pg = pooled + (size_t)g * 1156;
        for (int i = threadIdx.x; i < 1156; i += 256) {
            int plane = (i * 29027) >> 23;          // i/289
            int pos = i - plane * 289;
            int h = (pos * 3856) >> 16;             // pos/17
            int w = pos - h * 17;
            const float* qp = q + plane * 289;
            float s = 0.f;
#pragma unroll
            for (int dh = -1; dh <= 1; ++dh) {
#pragma unroll
                for (int dw = -1; dw <= 1; ++dw) {
                    int hh = h + dh, ww = w + dw;
                    bool ok = ((unsigned)hh < 17u) & ((unsigned)ww < 17u);
                    s += ok ? qp[hh * 17 + ww] : 0.f;
                }
            }
            int si = (int)s;
            pg[i] = (short)si;
            int a = si < 0 ? -si : si;
            tmax = a > tmax ? a : tmax;
        }
    }
#pragma unroll
    for (int off = 32; off; off >>= 1) {
        int o = __shfl_down(tmax, off);
        tmax = o > tmax ? o : tmax;
    }
    int lane = threadIdx.x & 63, wv = threadIdx.x >> 6;
    if (lane == 0) smax[wv] = tmax;
    __syncthreads();
    if (threadIdx.x == 0) {
        int bm = smax[0];
        bm = smax[1] > bm ? smax[1] : bm;
        bm = smax[2] > bm ? smax[2] : bm;
        bm = smax[3] > bm ? smax[3] : bm;
        atomicMax((int*)(cnt + 1), bm);
    }
}

// BN-fold + per-channel weight quant -> bf16 image [kt][o][cc] linear; b_int, scale_o.
__global__ void k_weights(const float* __restrict__ conv_w,
                          const float* __restrict__ g,
                          const float* __restrict__ beta,
                          const float* __restrict__ mu,
                          const float* __restrict__ var,
                          const unsigned* __restrict__ cnt,
                          unsigned short* __restrict__ w_q,
                          float* __restrict__ b_int, float* __restrict__ scale_o) {
    const int o = blockIdx.x;
    const float stdv = sqrtf(var[o] + 1e-5f);
    const float r = g[o] / stdv;
    const float* wo = conv_w + o * C_;
    float m = 0.f;
    for (int c = threadIdx.x; c < C_; c += 256) m = fmaxf(m, fabsf(wo[c] * r));
#pragma unroll
    for (int off = 32; off; off >>= 1) m = fmaxf(m, __shfl_down(m, off));
    __shared__ float sm[4];
    __shared__ float swsf;
    int lane = threadIdx.x & 63, wv = threadIdx.x >> 6;
    if (lane == 0) sm[wv] = m;
    __syncthreads();
    if (threadIdx.x == 0) {
        float bm = fmaxf(fmaxf(sm[0], sm[1]), fmaxf(sm[2], sm[3]));
        swsf = fmaxf(bm / QN_, 1e-8f);
    }
    __syncthreads();
    const float wsf = swsf;
    for (int c = threadIdx.x; c < C_; c += 256) {
        float wi = rintf(wo[c] * r / wsf);
        wi = fminf(fmaxf(wi, -128.f), 127.f);
        // integers |v|<=128 are exact in bf16: truncate f32 bits
        w_q[(c >> 5) * 6144 + o * 32 + (c & 31)] =
            (unsigned short)(__float_as_uint(wi) >> 16);
    }
    if (threadIdx.x == 0) {
        float s0 = fmaxf(__uint_as_float(cnt[0]) / QN_, 1e-8f);
        float maxx2 = ((float)((const int*)cnt)[1] / 9.0f) * s0;
        float s1 = fmaxf(maxx2 / QN_, 1e-8f);
        float bf = beta[o] - g[o] * mu[o] / stdv;
        b_int[o] = rintf(bf / (wsf * s1));
        scale_o[o] = wsf * s1;
    }
}

// Exact xi LUT: p in [-1152,1152] -> bf16(clip(rint(((p/9)*s0)/s1)))
__global__ void k_lut(const unsigned* __restrict__ cnt, unsigned short* __restrict__ lut) {
    const float s0 = fmaxf(__uint_as_float(cnt[0]) / QN_, 1e-8f);
    const float maxx2 = ((float)((const int*)cnt)[1] / 9.0f) * s0;
    const float s1 = fmaxf(maxx2 / QN_, 1e-8f);
    for (int i = threadIdx.x; i < 2305; i += 256) {
        float p = (float)(i - 1152);
        float t = (p / 9.0f) * s0;
        float v = rintf(t / s1);
        v = fminf(fmaxf(v, -128.f), 127.f);
        lut[i] = (unsigned short)(__float_as_uint(v) >> 16);
    }
}

// MFMA GEMM: out[b,o,hw] = relu((sum_c xi*w_int + b_int[o]) * scale_o[o])
// Block = (hw-half, batch): 192 x 160 output. 8 waves as 4(o) x 2(hw),
// wave tile 48x80 = 3x5 frags of 16x16, K staged 32/step.
__launch_bounds__(512) __global__
void k_gemm(const short* __restrict__ pooled,
            const unsigned short* __restrict__ w_q,
            const unsigned short* __restrict__ lut_g,
            const float* __restrict__ b_int, const float* __restrict__ scale_o,
            unsigned* cnt, float* __restrict__ out) {
    __shared__ char sW[12288];          // [192][32] bf16, XOR-swizzled
    __shared__ char sX[10240];          // [160][32] bf16 (hw-major), XOR-swizzled
    __shared__ unsigned short s_lut[2305];
    __shared__ float red[8];
    const int tid = threadIdx.x;
    const int b = blockIdx.z;
    const int hw0 = blockIdx.x * 160;
    const int L = tid & 63;
    const int wv = tid >> 6;
    const int wo = (wv >> 1) * 48;
    const int whw = (wv & 1) * 80;
    const short* pooled_b = pooled + (size_t)b * C_ * HW_;

    for (int i = tid; i < 2305; i += 512) s_lut[i] = lut_g[i];

    f32x4 acc[3][5] = {};

    for (int kt = 0; kt < 24; ++kt) {
        __syncthreads();
        // ---- stage W: 12 x 1KB chunks via global_load_lds (inverse-swizzled source,
        //      linear LDS dest; read side applies SWZ) ----
        {
            int ldsoff = wv * 1024;
            const char* src = (const char*)w_q + kt * 12288 + SWZ(ldsoff + L * 16);
            __builtin_amdgcn_global_load_lds(
                (const __attribute__((address_space(1))) unsigned int*)src,
                (__attribute__((address_space(3))) unsigned int*)(sW + ldsoff),
                16, 0, 0);
            if (wv < 4) {
                int ldsoff2 = (wv + 8) * 1024;
                const char* src2 = (const char*)w_q + kt * 12288 + SWZ(ldsoff2 + L * 16);
                __builtin_amdgcn_global_load_lds(
                    (const __attribute__((address_space(1))) unsigned int*)src2,
                    (__attribute__((address_space(3))) unsigned int*)(sW + ldsoff2),
                    16, 0, 0);
            }
        }
        // ---- stage X: 160 hw x 32 c, int16 -> xi bf16 via LUT, transposed ----
        for (int u = tid; u < 640; u += 512) {
            int cg = u / 160;
            int hwr = u - cg * 160;
            int hw = hw0 + hwr;
            unsigned vv0 = 0, vv1 = 0, vv2 = 0, vv3 = 0;
            if (hw < HW_) {
                const short* src = pooled_b + (size_t)(kt * 32 + cg * 8) * HW_ + hw;
                unsigned q0 = s_lut[1152 + src[0 * HW_]];
                unsigned q1 = s_lut[1152 + src[1 * HW_]];
                unsigned q2 = s_lut[1152 + src[2 * HW_]];
                unsigned q3 = s_lut[1152 + src[3 * HW_]];
                unsigned q4 = s_lut[1152 + src[4 * HW_]];
                unsigned q5 = s_lut[1152 + src[5 * HW_]];
                unsigned q6 = s_lut[1152 + src[6 * HW_]];
                unsigned q7 = s_lut[1152 + src[7 * HW_]];
                vv0 = q0 | (q1 << 16);
                vv1 = q2 | (q3 << 16);
                vv2 = q4 | (q5 << 16);
                vv3 = q6 | (q7 << 16);
            }
            uint4 q4v;
            q4v.x = vv0; q4v.y = vv1; q4v.z = vv2; q4v.w = vv3;
            *(uint4*)(sX + SWZ(hwr * 64 + cg * 16)) = q4v;
        }
        __syncthreads();
        // ---- fragments + MFMA ----
        bf16x8 af[3], bfr[5];
#pragma unroll
        for (int m = 0; m < 3; ++m)
            af[m] = *(const bf16x8*)(sW +
                SWZ((wo + m * 16 + (L & 15)) * 64 + (L >> 4) * 16));
#pragma unroll
        for (int n = 0; n < 5; ++n)
            bfr[n] = *(const bf16x8*)(sX +
                SWZ((whw + n * 16 + (L & 15)) * 64 + (L >> 4) * 16));
#pragma unroll
        for (int m = 0; m < 3; ++m)
#pragma unroll
            for (int n = 0; n < 5; ++n)
                acc[m][n] = __builtin_amdgcn_mfma_f32_16x16x32_bf16(
                    af[m], bfr[n], acc[m][n], 0, 0, 0);
    }

    // ---- epilogue: bias, scale, relu, store, track max ----
    float lmax = 0.f;
#pragma unroll
    for (int m = 0; m < 3; ++m) {
        int ob = wo + m * 16 + (L >> 4) * 4;
        float bi0 = b_int[ob + 0], bi1 = b_int[ob + 1];
        float bi2 = b_int[ob + 2], bi3 = b_int[ob + 3];
        float sc0 = scale_o[ob + 0], sc1 = scale_o[ob + 1];
        float sc2 = scale_o[ob + 2], sc3 = scale_o[ob + 3];
#pragma unroll
        for (int n = 0; n < 5; ++n) {
            int hw = hw0 + whw + n * 16 + (L & 15);
            if (hw < HW_) {
                size_t base = ((size_t)b * O_ + ob) * HW_ + hw;
                float v0 = fmaxf((acc[m][n][0] + bi0) * sc0, 0.f);
                float v1 = fmaxf((acc[m][n][1] + bi1) * sc1, 0.f);
                float v2 = fmaxf((acc[m][n][2] + bi2) * sc2, 0.f);
                float v3 = fmaxf((acc[m][n][3] + bi3) * sc3, 0.f);
                out[base + 0 * HW_] = v0;
                out[base + 1 * HW_] = v1;
                out[base + 2 * HW_] = v2;
                out[base + 3 * HW_] = v3;
                lmax = fmaxf(fmaxf(fmaxf(v0, v1), fmaxf(v2, v3)), lmax);
            }
        }
    }
#pragma unroll
    for (int off = 32; off; off >>= 1) lmax = fmaxf(lmax, __shfl_down(lmax, off));
    if (L == 0) red[wv] = lmax;
    __syncthreads();
    if (tid == 0) {
        float bm = red[0];
#pragma unroll
        for (int i = 1; i < 8; ++i) bm = fmaxf(bm, red[i]);
        atomicMax(cnt + 2, __float_as_uint(bm));
    }
}

__global__ void k_quant_out(float* __restrict__ out, const unsigned* __restrict__ cnt) {
    const float s2 = fmaxf(__uint_as_float(cnt[2]) / QN_, 1e-8f);
    float4* o4 = (float4*)out;
    const int n4 = N_OUT / 4;
    for (int i = blockIdx.x * blockDim.x + threadIdx.x; i < n4;
         i += gridDim.x * blockDim.x) {
        float4 v = o4[i];
        v.x = fminf(fmaxf(rintf(v.x / s2), -128.f), 127.f) * s2;
        v.y = fminf(fmaxf(rintf(v.y / s2), -128.f), 127.f) * s2;
        v.z = fminf(fmaxf(rintf(v.z / s2), -128.f), 127.f) * s2;
        v.w = fminf(fmaxf(rintf(v.w / s2), -128.f), 127.f) * s2;
        o4[i] = v;
    }
    if (blockIdx.x == 0 && threadIdx.x == 0) out[N_OUT] = s2;
}

extern "C" void kernel_launch(void* const* d_in, const int* in_sizes, int n_in,
                              void* d_out, int out_size, void* d_ws, size_t ws_size,
                              hipStream_t stream) {
    const float* x      = (const float*)d_in[0];
    const float* conv_w = (const float*)d_in[1];
    const float* g      = (const float*)d_in[2];
    const float* beta   = (const float*)d_in[3];
    const float* mu     = (const float*)d_in[4];
    const float* var    = (const float*)d_in[5];
    float* out = (float*)d_out;

    char* wsb = (char*)d_ws;
    unsigned* cnt          = (unsigned*)wsb;
    float* b_int           = (float*)(wsb + 1024);
    float* scale_o         = (float*)(wsb + 2048);
    unsigned short* lut    = (unsigned short*)(wsb + 3072);
    unsigned short* w_q    = (unsigned short*)(wsb + 8192);
    short* pooled          = (short*)(wsb + (1u << 20));

    k_init<<<1, 64, 0, stream>>>(cnt);
    k_absmax_x<<<2048, 256, 0, stream>>>((const float4*)x, N_IN / 4, cnt);
    k_quant_pool<<<2048, 256, 0, stream>>>(x, pooled, cnt);
    k_weights<<<O_, 256, 0, stream>>>(conv_w, g, beta, mu, var, cnt, w_q, b_int,
                                      scale_o);
    k_lut<<<1, 256, 0, stream>>>(cnt, lut);
    dim3 ggrid(2, 1, B_);
    k_gemm<<<ggrid, 512, 0, stream>>>(pooled, w_q, lut, b_int, scale_o, cnt, out);
    k_quant_out<<<2048, 256, 0, stream>>>(out, cnt);
}